// Round 2
// baseline (2363.604 us; speedup 1.0000x reference)
//
#include <hip/hip_runtime.h>

__device__ __forceinline__ float bcast(float v, int l) {
    return __uint_as_float(__builtin_amdgcn_readlane(__float_as_uint(v), (unsigned)l));
}
__device__ __forceinline__ float sigm(float x) { return 1.0f / (1.0f + expf(-x)); }

// ---------------------------------------------------------------------------
// K1: dist[256][8192] = input[256][512] @ akey[8192][512]^T   (NT GEMM, fp32)
// ---------------------------------------------------------------------------
__global__ __launch_bounds__(256) void k_dist(const float* __restrict__ A,
                                              const float* __restrict__ Bm,
                                              float* __restrict__ C) {
    __shared__ float As[32][68];
    __shared__ float Bs[32][132];
    const int n0 = blockIdx.x * 128;
    const int m0 = blockIdx.y * 64;
    const int tid = threadIdx.x;
    const int tx = tid & 15;
    const int ty = tid >> 4;
    const int lm = tid >> 3;
    const int lk = (tid & 7) * 4;
    float acc[4][8];
#pragma unroll
    for (int i = 0; i < 4; ++i)
#pragma unroll
        for (int j = 0; j < 8; ++j) acc[i][j] = 0.0f;

    for (int kt = 0; kt < 512; kt += 32) {
        __syncthreads();
#pragma unroll
        for (int r = 0; r < 2; ++r) {
            int m = lm + 32 * r;
            float4 v = *(const float4*)&A[(size_t)(m0 + m) * 512 + kt + lk];
            As[lk + 0][m] = v.x; As[lk + 1][m] = v.y;
            As[lk + 2][m] = v.z; As[lk + 3][m] = v.w;
        }
#pragma unroll
        for (int r = 0; r < 4; ++r) {
            int n = lm + 32 * r;
            float4 v = *(const float4*)&Bm[(size_t)(n0 + n) * 512 + kt + lk];
            Bs[lk + 0][n] = v.x; Bs[lk + 1][n] = v.y;
            Bs[lk + 2][n] = v.z; Bs[lk + 3][n] = v.w;
        }
        __syncthreads();
#pragma unroll
        for (int k = 0; k < 32; ++k) {
            float4 a4 = *(const float4*)&As[k][ty * 4];
            float4 b0 = *(const float4*)&Bs[k][tx * 8];
            float4 b1 = *(const float4*)&Bs[k][tx * 8 + 4];
            float av[4] = {a4.x, a4.y, a4.z, a4.w};
            float bv[8] = {b0.x, b0.y, b0.z, b0.w, b1.x, b1.y, b1.z, b1.w};
#pragma unroll
            for (int i = 0; i < 4; ++i)
#pragma unroll
                for (int j = 0; j < 8; ++j)
                    acc[i][j] = fmaf(av[i], bv[j], acc[i][j]);
        }
    }
#pragma unroll
    for (int i = 0; i < 4; ++i) {
        size_t row = (size_t)(m0 + ty * 4 + i) * 8192 + n0 + tx * 8;
        *(float4*)&C[row]     = make_float4(acc[i][0], acc[i][1], acc[i][2], acc[i][3]);
        *(float4*)&C[row + 4] = make_float4(acc[i][4], acc[i][5], acc[i][6], acc[i][7]);
    }
}

// ---------------------------------------------------------------------------
// K2: per-row argmax (first index on ties) -> set 0 -> softmax, in place
// ---------------------------------------------------------------------------
__global__ __launch_bounds__(256) void k_softmax(float* __restrict__ D) {
    __shared__ float row[8192];
    __shared__ float rv[256];
    __shared__ int   ri[256];
    const int b = blockIdx.x, tid = threadIdx.x;
    float* dr = D + (size_t)b * 8192;
    for (int i = tid; i < 2048; i += 256)
        *(float4*)&row[i * 4] = *(const float4*)&dr[i * 4];
    __syncthreads();

    float bv = -INFINITY; int bi = 0x7fffffff;
    for (int i = tid; i < 8192; i += 256) {
        float v = row[i];
        if (v > bv || (v == bv && i < bi)) { bv = v; bi = i; }
    }
    rv[tid] = bv; ri[tid] = bi;
    __syncthreads();
    for (int s = 128; s > 0; s >>= 1) {
        if (tid < s) {
            float ov = rv[tid + s]; int oi = ri[tid + s];
            if (ov > rv[tid] || (ov == rv[tid] && oi < ri[tid])) { rv[tid] = ov; ri[tid] = oi; }
        }
        __syncthreads();
    }
    if (tid == 0) row[ri[0]] = 0.0f;
    __syncthreads();

    float m = -INFINITY;
    for (int i = tid; i < 8192; i += 256) m = fmaxf(m, row[i]);
    rv[tid] = m;
    __syncthreads();
    for (int s = 128; s > 0; s >>= 1) {
        if (tid < s) rv[tid] = fmaxf(rv[tid], rv[tid + s]);
        __syncthreads();
    }
    const float M = rv[0];
    __syncthreads();

    float ssum = 0.0f;
    for (int i = tid; i < 8192; i += 256) {
        float e = expf(row[i] - M);
        row[i] = e;
        ssum += e;
    }
    rv[tid] = ssum;
    __syncthreads();
    for (int s = 128; s > 0; s >>= 1) {
        if (tid < s) rv[tid] += rv[tid + s];
        __syncthreads();
    }
    const float inv = 1.0f / rv[0];
    for (int i = tid; i < 2048; i += 256) {
        float4 v = *(float4*)&row[i * 4];
        v.x *= inv; v.y *= inv; v.z *= inv; v.w *= inv;
        *(float4*)&dr[i * 4] = v;
    }
}

// ---------------------------------------------------------------------------
// K3: hist[256][544] += a[256][8192] @ aval[8192][544]  (NN GEMM, split-K=8)
// ---------------------------------------------------------------------------
__global__ __launch_bounds__(256) void k_hist(const float* __restrict__ A,
                                              const float* __restrict__ Bm,
                                              float* __restrict__ C) {
    __shared__ float As[32][68];
    __shared__ float Bs[32][68];
    const int n0 = blockIdx.x * 64;
    const int m0 = blockIdx.y * 64;
    const int kz = blockIdx.z;
    const int tid = threadIdx.x;
    const int tx = tid & 15, ty = tid >> 4;
    const int lr = tid >> 3;
    const int lq = (tid & 7) * 4;
    float acc[4][4];
#pragma unroll
    for (int i = 0; i < 4; ++i)
#pragma unroll
        for (int j = 0; j < 4; ++j) acc[i][j] = 0.0f;

    const int k_lo = kz * 1024, k_hi = k_lo + 1024;
    for (int kt = k_lo; kt < k_hi; kt += 32) {
        __syncthreads();
#pragma unroll
        for (int r = 0; r < 2; ++r) {
            int m = lr + 32 * r;
            float4 v = *(const float4*)&A[(size_t)(m0 + m) * 8192 + kt + lq];
            As[lq + 0][m] = v.x; As[lq + 1][m] = v.y;
            As[lq + 2][m] = v.z; As[lq + 3][m] = v.w;
        }
#pragma unroll
        for (int r = 0; r < 2; ++r) {
            int kk = (tid >> 4) + 16 * r;
            int nq = (tid & 15) * 4;
            float4 v = make_float4(0.f, 0.f, 0.f, 0.f);
            if (n0 + nq < 544)
                v = *(const float4*)&Bm[(size_t)(kt + kk) * 544 + n0 + nq];
            *(float4*)&Bs[kk][nq] = v;
        }
        __syncthreads();
#pragma unroll
        for (int k = 0; k < 32; ++k) {
            float4 a4 = *(const float4*)&As[k][ty * 4];
            float4 b4 = *(const float4*)&Bs[k][tx * 4];
            float av[4] = {a4.x, a4.y, a4.z, a4.w};
            float bv[4] = {b4.x, b4.y, b4.z, b4.w};
#pragma unroll
            for (int i = 0; i < 4; ++i)
#pragma unroll
                for (int j = 0; j < 4; ++j)
                    acc[i][j] = fmaf(av[i], bv[j], acc[i][j]);
        }
    }
#pragma unroll
    for (int i = 0; i < 4; ++i)
#pragma unroll
        for (int j = 0; j < 4; ++j) {
            int n = n0 + tx * 4 + j;
            if (n < 544)
                atomicAdd(&C[(size_t)(m0 + ty * 4 + i) * 544 + n], acc[i][j]);
        }
}

// ---------------------------------------------------------------------------
// K4: x[b][t][o] = tanh(b1[o] + W1[o][0]*input[b][t] + sum_j W1[o][1+j]*hist[b][t+j])
// ---------------------------------------------------------------------------
__global__ __launch_bounds__(256) void k_xfeat(const float* __restrict__ inp,
                                               const float* __restrict__ hist,
                                               const float* __restrict__ W1,
                                               const float* __restrict__ b1,
                                               float* __restrict__ X) {
    __shared__ float w[33 * 64];
    __shared__ float bl[64];
    __shared__ float il[128];
    __shared__ float hl[160];
    const int t0 = blockIdx.x * 128;
    const int b  = blockIdx.y;
    const int tid = threadIdx.x;
    for (int idx = tid; idx < 2112; idx += 256) {
        int o = idx / 33, k = idx % 33;
        w[k * 64 + o] = W1[idx];
    }
    if (tid < 64) bl[tid] = b1[tid];
    if (tid < 128) il[tid] = inp[(size_t)b * 512 + t0 + tid];
    for (int i = tid; i < 159; i += 256) hl[i] = hist[(size_t)b * 544 + t0 + i];
    __syncthreads();
    const int o = tid & 63, tq = tid >> 6;
    for (int it = 0; it < 32; ++it) {
        int tl = it * 4 + tq;
        float acc = fmaf(il[tl], w[o], bl[o]);
#pragma unroll
        for (int j = 0; j < 32; ++j)
            acc = fmaf(hl[tl + j], w[(1 + j) * 64 + o], acc);
        X[(size_t)(b * 512 + t0 + tl) * 64 + o] = tanhf(acc);
    }
}

// ---------------------------------------------------------------------------
// K5: LSTM layer 0 recurrence over one t-chunk, split-K over 2 thread-halves.
// 1024 threads: g = tid&511 (gate row), half = tid>>9.
// half0: Wih0[g][0:64] + Whh0[g][0:32]  (96 regs)
// half1: Whh0[g][32:128]                (96 regs)
// Partial sums meet in gl[2][512]; threads<128 do activations.
// ---------------------------------------------------------------------------
__global__ __launch_bounds__(1024, 4) void k_rec0(const float* __restrict__ X,
                                                  const float* __restrict__ Wih,
                                                  const float* __restrict__ Whh,
                                                  const float* __restrict__ bih,
                                                  const float* __restrict__ bhh,
                                                  float* __restrict__ H0c,
                                                  float* __restrict__ S,
                                                  int t0, int TC) {
    __shared__ float hl[128];
    __shared__ float gl[2][512];
    const int b = blockIdx.x;
    const int tid = threadIdx.x;
    const int g = tid & 511;
    const int half = tid >> 9;
    const int lane = tid & 63;
    float w[96];
    if (half == 0) {
#pragma unroll
        for (int k = 0; k < 64; ++k) w[k] = Wih[(size_t)g * 64 + k];
#pragma unroll
        for (int j = 0; j < 32; ++j) w[64 + j] = Whh[(size_t)g * 128 + j];
    } else {
#pragma unroll
        for (int j = 0; j < 96; ++j) w[j] = Whh[(size_t)g * 128 + 32 + j];
    }
    const float bias = bih[g] + bhh[g];
    float c = 0.0f;
    if (tid < 128) {
        hl[tid] = S[(size_t)b * 128 + tid];
        c = S[32768 + (size_t)b * 128 + tid];
    }
    __syncthreads();
    const float* xb = X + (size_t)b * 512 * 64 + (size_t)t0 * 64;
    float* hb = H0c + (size_t)b * TC * 128;
    float vx = xb[lane];
    for (int tl = 0; tl < TC; ++tl) {
        float vxn = xb[(size_t)(tl + 1) * 64 + lane];  // X padded by 64
        float vh0 = hl[lane];
        float vh1 = hl[64 + lane];
        float a0 = 0.f, a1 = 0.f, a2 = 0.f, a3 = 0.f;
        if (half == 0) {
#pragma unroll
            for (int k = 0; k < 64; k += 4) {
                a0 = fmaf(bcast(vx, k + 0), w[k + 0], a0);
                a1 = fmaf(bcast(vx, k + 1), w[k + 1], a1);
                a2 = fmaf(bcast(vx, k + 2), w[k + 2], a2);
                a3 = fmaf(bcast(vx, k + 3), w[k + 3], a3);
            }
#pragma unroll
            for (int j = 0; j < 32; j += 4) {
                a0 = fmaf(bcast(vh0, j + 0), w[64 + j + 0], a0);
                a1 = fmaf(bcast(vh0, j + 1), w[64 + j + 1], a1);
                a2 = fmaf(bcast(vh0, j + 2), w[64 + j + 2], a2);
                a3 = fmaf(bcast(vh0, j + 3), w[64 + j + 3], a3);
            }
            gl[0][g] = bias + ((a0 + a1) + (a2 + a3));
        } else {
#pragma unroll
            for (int j = 0; j < 32; j += 4) {
                a0 = fmaf(bcast(vh0, 32 + j + 0), w[j + 0], a0);
                a1 = fmaf(bcast(vh0, 32 + j + 1), w[j + 1], a1);
                a2 = fmaf(bcast(vh0, 32 + j + 2), w[j + 2], a2);
                a3 = fmaf(bcast(vh0, 32 + j + 3), w[j + 3], a3);
            }
#pragma unroll
            for (int j = 0; j < 64; j += 4) {
                a0 = fmaf(bcast(vh1, j + 0), w[32 + j + 0], a0);
                a1 = fmaf(bcast(vh1, j + 1), w[32 + j + 1], a1);
                a2 = fmaf(bcast(vh1, j + 2), w[32 + j + 2], a2);
                a3 = fmaf(bcast(vh1, j + 3), w[32 + j + 3], a3);
            }
            gl[1][g] = (a0 + a1) + (a2 + a3);
        }
        __syncthreads();
        if (tid < 128) {
            float iv = sigm(gl[0][tid]       + gl[1][tid]);
            float fv = sigm(gl[0][128 + tid] + gl[1][128 + tid]);
            float gv = tanhf(gl[0][256 + tid] + gl[1][256 + tid]);
            float ov = sigm(gl[0][384 + tid] + gl[1][384 + tid]);
            c = fv * c + iv * gv;
            float h = ov * tanhf(c);
            hl[tid] = h;
            hb[(size_t)tl * 128 + tid] = h;
        }
        __syncthreads();
        vx = vxn;
    }
    if (tid < 128) {
        S[(size_t)b * 128 + tid] = hl[tid];
        S[32768 + (size_t)b * 128 + tid] = c;
    }
}

// ---------------------------------------------------------------------------
// K6: P[m][g] = bih1[g]+bhh1[g] + H0c[m][:] · Wih1[g][:]   (NT GEMM, K=128)
// M = 256*TC rows. Tile 64x128x32, 256 threads, 4x8 micro.
// ---------------------------------------------------------------------------
__global__ __launch_bounds__(256) void k_pre1gemm(const float* __restrict__ A,
                                                  const float* __restrict__ Bm,
                                                  const float* __restrict__ bih,
                                                  const float* __restrict__ bhh,
                                                  float* __restrict__ C) {
    __shared__ float As[32][68];
    __shared__ float Bs[32][132];
    const int n0 = blockIdx.x * 128;
    const int m0 = blockIdx.y * 64;
    const int tid = threadIdx.x;
    const int tx = tid & 15;
    const int ty = tid >> 4;
    const int lm = tid >> 3;
    const int lk = (tid & 7) * 4;
    float acc[4][8];
#pragma unroll
    for (int i = 0; i < 4; ++i)
#pragma unroll
        for (int j = 0; j < 8; ++j) acc[i][j] = 0.0f;

    for (int kt = 0; kt < 128; kt += 32) {
        __syncthreads();
#pragma unroll
        for (int r = 0; r < 2; ++r) {
            int m = lm + 32 * r;
            float4 v = *(const float4*)&A[(size_t)(m0 + m) * 128 + kt + lk];
            As[lk + 0][m] = v.x; As[lk + 1][m] = v.y;
            As[lk + 2][m] = v.z; As[lk + 3][m] = v.w;
        }
#pragma unroll
        for (int r = 0; r < 4; ++r) {
            int n = lm + 32 * r;
            float4 v = *(const float4*)&Bm[(size_t)(n0 + n) * 128 + kt + lk];
            Bs[lk + 0][n] = v.x; Bs[lk + 1][n] = v.y;
            Bs[lk + 2][n] = v.z; Bs[lk + 3][n] = v.w;
        }
        __syncthreads();
#pragma unroll
        for (int k = 0; k < 32; ++k) {
            float4 a4 = *(const float4*)&As[k][ty * 4];
            float4 b0 = *(const float4*)&Bs[k][tx * 8];
            float4 b1 = *(const float4*)&Bs[k][tx * 8 + 4];
            float av[4] = {a4.x, a4.y, a4.z, a4.w};
            float bv[8] = {b0.x, b0.y, b0.z, b0.w, b1.x, b1.y, b1.z, b1.w};
#pragma unroll
            for (int i = 0; i < 4; ++i)
#pragma unroll
                for (int j = 0; j < 8; ++j)
                    acc[i][j] = fmaf(av[i], bv[j], acc[i][j]);
        }
    }
    float bb[8];
#pragma unroll
    for (int j = 0; j < 8; ++j) {
        int n = n0 + tx * 8 + j;
        bb[j] = bih[n] + bhh[n];
    }
#pragma unroll
    for (int i = 0; i < 4; ++i) {
        size_t row = (size_t)(m0 + ty * 4 + i) * 512 + n0 + tx * 8;
        *(float4*)&C[row]     = make_float4(acc[i][0] + bb[0], acc[i][1] + bb[1],
                                            acc[i][2] + bb[2], acc[i][3] + bb[3]);
        *(float4*)&C[row + 4] = make_float4(acc[i][4] + bb[4], acc[i][5] + bb[5],
                                            acc[i][6] + bb[6], acc[i][7] + bb[7]);
    }
}

// ---------------------------------------------------------------------------
// K7: LSTM layer 1 recurrence over one t-chunk, split-K over 2 thread-halves.
// half h: Whh1[g][h*64 : h*64+64]  (64 regs).  vp (pregate incl. bias) read by half0.
// ---------------------------------------------------------------------------
__global__ __launch_bounds__(1024, 4) void k_rec1(const float* __restrict__ P,
                                                  const float* __restrict__ Whh,
                                                  float* __restrict__ S,
                                                  int TC) {
    __shared__ float hl[128];
    __shared__ float gl[2][512];
    const int b = blockIdx.x;
    const int tid = threadIdx.x;
    const int g = tid & 511;
    const int half = tid >> 9;
    const int lane = tid & 63;
    float w[64];
#pragma unroll
    for (int j = 0; j < 64; ++j) w[j] = Whh[(size_t)g * 128 + half * 64 + j];
    float c = 0.0f;
    if (tid < 128) {
        hl[tid] = S[(size_t)b * 128 + tid];
        c = S[32768 + (size_t)b * 128 + tid];
    }
    __syncthreads();
    const float* pb = P + (size_t)b * TC * 512;
    float vp = (half == 0) ? pb[g] : 0.0f;
    for (int tl = 0; tl < TC; ++tl) {
        float vpn = (half == 0) ? pb[(size_t)(tl + 1) * 512 + g] : 0.0f;  // P padded
        float vh = (half == 0) ? hl[lane] : hl[64 + lane];
        float a0 = 0.f, a1 = 0.f, a2 = 0.f, a3 = 0.f;
#pragma unroll
        for (int j = 0; j < 64; j += 4) {
            a0 = fmaf(bcast(vh, j + 0), w[j + 0], a0);
            a1 = fmaf(bcast(vh, j + 1), w[j + 1], a1);
            a2 = fmaf(bcast(vh, j + 2), w[j + 2], a2);
            a3 = fmaf(bcast(vh, j + 3), w[j + 3], a3);
        }
        gl[half][g] = vp + ((a0 + a1) + (a2 + a3));
        __syncthreads();
        if (tid < 128) {
            float iv = sigm(gl[0][tid]       + gl[1][tid]);
            float fv = sigm(gl[0][128 + tid] + gl[1][128 + tid]);
            float gv = tanhf(gl[0][256 + tid] + gl[1][256 + tid]);
            float ov = sigm(gl[0][384 + tid] + gl[1][384 + tid]);
            c = fv * c + iv * gv;
            float h = ov * tanhf(c);
            hl[tid] = h;
        }
        __syncthreads();
        vp = vpn;
    }
    if (tid < 128) {
        S[(size_t)b * 128 + tid] = hl[tid];
        S[32768 + (size_t)b * 128 + tid] = c;
    }
}

// ---------------------------------------------------------------------------
// K8: tail head: out = tanh(tanh(h1_last) @ W2^T + b2) @ W3^T + b3
// ---------------------------------------------------------------------------
__global__ __launch_bounds__(64) void k_tail(const float* __restrict__ Hs,
                                             const float* __restrict__ W2,
                                             const float* __restrict__ b2,
                                             const float* __restrict__ W3,
                                             const float* __restrict__ b3,
                                             float* __restrict__ out) {
    __shared__ float last[128], l2s[64];
    const int b = blockIdx.x, tid = threadIdx.x;
    last[tid]      = tanhf(Hs[(size_t)b * 128 + tid]);
    last[tid + 64] = tanhf(Hs[(size_t)b * 128 + 64 + tid]);
    __syncthreads();
    float acc = b2[tid];
#pragma unroll 4
    for (int j = 0; j < 128; ++j) acc = fmaf(W2[(size_t)tid * 128 + j], last[j], acc);
    l2s[tid] = tanhf(acc);
    __syncthreads();
    if (tid < 32) {
        float a2 = b3[tid];
#pragma unroll 4
        for (int o = 0; o < 64; ++o) a2 = fmaf(W3[(size_t)tid * 64 + o], l2s[o], a2);
        out[(size_t)b * 32 + tid] = a2;
    }
}

// ---------------------------------------------------------------------------
extern "C" void kernel_launch(void* const* d_in, const int* in_sizes, int n_in,
                              void* d_out, int out_size, void* d_ws, size_t ws_size,
                              hipStream_t stream) {
    (void)in_sizes; (void)n_in; (void)out_size;
    const float* inp  = (const float*)d_in[0];
    const float* akey = (const float*)d_in[1];
    const float* aval = (const float*)d_in[2];
    const float* W1   = (const float*)d_in[3];
    const float* b1   = (const float*)d_in[4];
    const float* Wih0 = (const float*)d_in[5];
    const float* Whh0 = (const float*)d_in[6];
    const float* bih0 = (const float*)d_in[7];
    const float* bhh0 = (const float*)d_in[8];
    const float* Wih1 = (const float*)d_in[9];
    const float* Whh1 = (const float*)d_in[10];
    const float* bih1 = (const float*)d_in[11];
    const float* bhh1 = (const float*)d_in[12];
    const float* W2   = (const float*)d_in[13];
    const float* b2   = (const float*)d_in[14];
    const float* W3   = (const float*)d_in[15];
    const float* b3   = (const float*)d_in[16];

    float* ws   = (float*)d_ws;
    float* dist = ws;                       // 2,097,152
    float* hist = dist + 2097152;           //   139,264
    float* X    = hist + 139264;            // 8,388,608 + 64 pad
    float* S0   = X + 8388672;              //    65,536 (h then c)
    float* S1   = S0 + 65536;               //    65,536
    float* H0c  = S1 + 65536;               // 256*TC*128
    // P follows H0c; both sized by TC
    const size_t fixed = (size_t)(H0c - ws);

    int TC = 32;
    if ((fixed + 131072ull * 128 / 2 /*H0c@TC? placeholder*/) * 0) {}  // (no-op)
    // bytes needed for TC: (fixed + 256*TC*128 + 256*TC*512 + 512) * 4
    if ((fixed + 32768ull * 128 + 131072ull * 128 + 512) * 4 <= ws_size)      TC = 128;
    else if ((fixed + 32768ull * 64 + 131072ull * 64 + 512) * 4 <= ws_size)   TC = 64;
    float* P = H0c + (size_t)256 * TC * 128;

    k_dist<<<dim3(64, 4), 256, 0, stream>>>(inp, akey, dist);
    k_softmax<<<256, 256, 0, stream>>>(dist);
    hipMemsetAsync(hist, 0, 139264 * 4, stream);
    k_hist<<<dim3(9, 4, 8), 256, 0, stream>>>(dist, aval, hist);
    k_xfeat<<<dim3(4, 256), 256, 0, stream>>>(inp, hist, W1, b1, X);
    hipMemsetAsync(S0, 0, (size_t)2 * 65536 * 4, stream);  // S0+S1 contiguous
    for (int t0 = 0; t0 < 512; t0 += TC) {
        k_rec0<<<256, 1024, 0, stream>>>(X, Wih0, Whh0, bih0, bhh0, H0c, S0, t0, TC);
        k_pre1gemm<<<dim3(4, 256 * TC / 64), 256, 0, stream>>>(H0c, Wih1, bih1, bhh1, P);
        k_rec1<<<256, 1024, 0, stream>>>(P, Whh1, S1, TC);
    }
    k_tail<<<256, 64, 0, stream>>>(S1, W2, b2, W3, b3, (float*)d_out);
}

// Round 3
// 1758.308 us; speedup vs baseline: 1.3442x; 1.3442x over previous
//
#include <hip/hip_runtime.h>

__device__ __forceinline__ float bcast(float v, int l) {
    return __uint_as_float(__builtin_amdgcn_readlane(__float_as_uint(v), (unsigned)l));
}
// Fast activations: v_exp_f32 / v_rcp_f32 based, ~1-2 ULP, overflow-safe.
__device__ __forceinline__ float fsigm(float x) {
    return __builtin_amdgcn_rcpf(1.0f + __expf(-x));
}
__device__ __forceinline__ float ftanh(float x) {
    float ax = fabsf(x);
    float e  = __expf(-2.0f * ax);                      // (0,1]
    float r  = (1.0f - e) * __builtin_amdgcn_rcpf(1.0f + e);
    return copysignf(r, x);
}

// ---------------------------------------------------------------------------
// K1: dist[256][8192] = input[256][512] @ akey[8192][512]^T   (NT GEMM, fp32)
// ---------------------------------------------------------------------------
__global__ __launch_bounds__(256) void k_dist(const float* __restrict__ A,
                                              const float* __restrict__ Bm,
                                              float* __restrict__ C) {
    __shared__ float As[32][68];
    __shared__ float Bs[32][132];
    const int n0 = blockIdx.x * 128;
    const int m0 = blockIdx.y * 64;
    const int tid = threadIdx.x;
    const int tx = tid & 15;
    const int ty = tid >> 4;
    const int lm = tid >> 3;
    const int lk = (tid & 7) * 4;
    float acc[4][8];
#pragma unroll
    for (int i = 0; i < 4; ++i)
#pragma unroll
        for (int j = 0; j < 8; ++j) acc[i][j] = 0.0f;

    for (int kt = 0; kt < 512; kt += 32) {
        __syncthreads();
#pragma unroll
        for (int r = 0; r < 2; ++r) {
            int m = lm + 32 * r;
            float4 v = *(const float4*)&A[(size_t)(m0 + m) * 512 + kt + lk];
            As[lk + 0][m] = v.x; As[lk + 1][m] = v.y;
            As[lk + 2][m] = v.z; As[lk + 3][m] = v.w;
        }
#pragma unroll
        for (int r = 0; r < 4; ++r) {
            int n = lm + 32 * r;
            float4 v = *(const float4*)&Bm[(size_t)(n0 + n) * 512 + kt + lk];
            Bs[lk + 0][n] = v.x; Bs[lk + 1][n] = v.y;
            Bs[lk + 2][n] = v.z; Bs[lk + 3][n] = v.w;
        }
        __syncthreads();
#pragma unroll
        for (int k = 0; k < 32; ++k) {
            float4 a4 = *(const float4*)&As[k][ty * 4];
            float4 b0 = *(const float4*)&Bs[k][tx * 8];
            float4 b1 = *(const float4*)&Bs[k][tx * 8 + 4];
            float av[4] = {a4.x, a4.y, a4.z, a4.w};
            float bv[8] = {b0.x, b0.y, b0.z, b0.w, b1.x, b1.y, b1.z, b1.w};
#pragma unroll
            for (int i = 0; i < 4; ++i)
#pragma unroll
                for (int j = 0; j < 8; ++j)
                    acc[i][j] = fmaf(av[i], bv[j], acc[i][j]);
        }
    }
#pragma unroll
    for (int i = 0; i < 4; ++i) {
        size_t row = (size_t)(m0 + ty * 4 + i) * 8192 + n0 + tx * 8;
        *(float4*)&C[row]     = make_float4(acc[i][0], acc[i][1], acc[i][2], acc[i][3]);
        *(float4*)&C[row + 4] = make_float4(acc[i][4], acc[i][5], acc[i][6], acc[i][7]);
    }
}

// ---------------------------------------------------------------------------
// K2: per-row argmax (first index on ties) -> set 0 -> softmax, in place
// ---------------------------------------------------------------------------
__global__ __launch_bounds__(256) void k_softmax(float* __restrict__ D) {
    __shared__ float row[8192];
    __shared__ float rv[256];
    __shared__ int   ri[256];
    const int b = blockIdx.x, tid = threadIdx.x;
    float* dr = D + (size_t)b * 8192;
    for (int i = tid; i < 2048; i += 256)
        *(float4*)&row[i * 4] = *(const float4*)&dr[i * 4];
    __syncthreads();

    float bv = -INFINITY; int bi = 0x7fffffff;
    for (int i = tid; i < 8192; i += 256) {
        float v = row[i];
        if (v > bv || (v == bv && i < bi)) { bv = v; bi = i; }
    }
    rv[tid] = bv; ri[tid] = bi;
    __syncthreads();
    for (int s = 128; s > 0; s >>= 1) {
        if (tid < s) {
            float ov = rv[tid + s]; int oi = ri[tid + s];
            if (ov > rv[tid] || (ov == rv[tid] && oi < ri[tid])) { rv[tid] = ov; ri[tid] = oi; }
        }
        __syncthreads();
    }
    if (tid == 0) row[ri[0]] = 0.0f;
    __syncthreads();

    float m = -INFINITY;
    for (int i = tid; i < 8192; i += 256) m = fmaxf(m, row[i]);
    rv[tid] = m;
    __syncthreads();
    for (int s = 128; s > 0; s >>= 1) {
        if (tid < s) rv[tid] = fmaxf(rv[tid], rv[tid + s]);
        __syncthreads();
    }
    const float M = rv[0];
    __syncthreads();

    float ssum = 0.0f;
    for (int i = tid; i < 8192; i += 256) {
        float e = __expf(row[i] - M);
        row[i] = e;
        ssum += e;
    }
    rv[tid] = ssum;
    __syncthreads();
    for (int s = 128; s > 0; s >>= 1) {
        if (tid < s) rv[tid] += rv[tid + s];
        __syncthreads();
    }
    const float inv = 1.0f / rv[0];
    for (int i = tid; i < 2048; i += 256) {
        float4 v = *(float4*)&row[i * 4];
        v.x *= inv; v.y *= inv; v.z *= inv; v.w *= inv;
        *(float4*)&dr[i * 4] = v;
    }
}

// ---------------------------------------------------------------------------
// K3: hist[256][544] += a[256][8192] @ aval[8192][544]  (NN GEMM, split-K=8)
// ---------------------------------------------------------------------------
__global__ __launch_bounds__(256) void k_hist(const float* __restrict__ A,
                                              const float* __restrict__ Bm,
                                              float* __restrict__ C) {
    __shared__ float As[32][68];
    __shared__ float Bs[32][68];
    const int n0 = blockIdx.x * 64;
    const int m0 = blockIdx.y * 64;
    const int kz = blockIdx.z;
    const int tid = threadIdx.x;
    const int tx = tid & 15, ty = tid >> 4;
    const int lr = tid >> 3;
    const int lq = (tid & 7) * 4;
    float acc[4][4];
#pragma unroll
    for (int i = 0; i < 4; ++i)
#pragma unroll
        for (int j = 0; j < 4; ++j) acc[i][j] = 0.0f;

    const int k_lo = kz * 1024, k_hi = k_lo + 1024;
    for (int kt = k_lo; kt < k_hi; kt += 32) {
        __syncthreads();
#pragma unroll
        for (int r = 0; r < 2; ++r) {
            int m = lr + 32 * r;
            float4 v = *(const float4*)&A[(size_t)(m0 + m) * 8192 + kt + lq];
            As[lq + 0][m] = v.x; As[lq + 1][m] = v.y;
            As[lq + 2][m] = v.z; As[lq + 3][m] = v.w;
        }
#pragma unroll
        for (int r = 0; r < 2; ++r) {
            int kk = (tid >> 4) + 16 * r;
            int nq = (tid & 15) * 4;
            float4 v = make_float4(0.f, 0.f, 0.f, 0.f);
            if (n0 + nq < 544)
                v = *(const float4*)&Bm[(size_t)(kt + kk) * 544 + n0 + nq];
            *(float4*)&Bs[kk][nq] = v;
        }
        __syncthreads();
#pragma unroll
        for (int k = 0; k < 32; ++k) {
            float4 a4 = *(const float4*)&As[k][ty * 4];
            float4 b4 = *(const float4*)&Bs[k][tx * 4];
            float av[4] = {a4.x, a4.y, a4.z, a4.w};
            float bv[4] = {b4.x, b4.y, b4.z, b4.w};
#pragma unroll
            for (int i = 0; i < 4; ++i)
#pragma unroll
                for (int j = 0; j < 4; ++j)
                    acc[i][j] = fmaf(av[i], bv[j], acc[i][j]);
        }
    }
#pragma unroll
    for (int i = 0; i < 4; ++i)
#pragma unroll
        for (int j = 0; j < 4; ++j) {
            int n = n0 + tx * 4 + j;
            if (n < 544)
                atomicAdd(&C[(size_t)(m0 + ty * 4 + i) * 544 + n], acc[i][j]);
        }
}

// ---------------------------------------------------------------------------
// K4: x[b][t][o] = tanh(b1[o] + W1[o][0]*input[b][t] + sum_j W1[o][1+j]*hist[b][t+j])
// ---------------------------------------------------------------------------
__global__ __launch_bounds__(256) void k_xfeat(const float* __restrict__ inp,
                                               const float* __restrict__ hist,
                                               const float* __restrict__ W1,
                                               const float* __restrict__ b1,
                                               float* __restrict__ X) {
    __shared__ float w[33 * 64];
    __shared__ float bl[64];
    __shared__ float il[128];
    __shared__ float hl[160];
    const int t0 = blockIdx.x * 128;
    const int b  = blockIdx.y;
    const int tid = threadIdx.x;
    for (int idx = tid; idx < 2112; idx += 256) {
        int o = idx / 33, k = idx % 33;
        w[k * 64 + o] = W1[idx];
    }
    if (tid < 64) bl[tid] = b1[tid];
    if (tid < 128) il[tid] = inp[(size_t)b * 512 + t0 + tid];
    for (int i = tid; i < 159; i += 256) hl[i] = hist[(size_t)b * 544 + t0 + i];
    __syncthreads();
    const int o = tid & 63, tq = tid >> 6;
    for (int it = 0; it < 32; ++it) {
        int tl = it * 4 + tq;
        float acc = fmaf(il[tl], w[o], bl[o]);
#pragma unroll
        for (int j = 0; j < 32; ++j)
            acc = fmaf(hl[tl + j], w[(1 + j) * 64 + o], acc);
        X[(size_t)(b * 512 + t0 + tl) * 64 + o] = ftanh(acc);
    }
}

// ---------------------------------------------------------------------------
// K5: P0[mc][g] = bih0[g]+bhh0[g] + X[row(mc)][:64] · Wih0[g][:64]  (NT, K=64)
// mc = chunk-local row; row(mc) = (mc>>tcs)*512 + t0 + (mc & (TC-1)).
// ---------------------------------------------------------------------------
__global__ __launch_bounds__(256) void k_pre0gemm(const float* __restrict__ A,
                                                  const float* __restrict__ Bm,
                                                  const float* __restrict__ bih,
                                                  const float* __restrict__ bhh,
                                                  float* __restrict__ C,
                                                  int t0, int tcs) {
    __shared__ float As[32][68];
    __shared__ float Bs[32][132];
    const int n0 = blockIdx.x * 128;
    const int m0 = blockIdx.y * 64;
    const int tid = threadIdx.x;
    const int tx = tid & 15;
    const int ty = tid >> 4;
    const int lm = tid >> 3;
    const int lk = (tid & 7) * 4;
    const int tcm = (1 << tcs) - 1;
    float acc[4][8];
#pragma unroll
    for (int i = 0; i < 4; ++i)
#pragma unroll
        for (int j = 0; j < 8; ++j) acc[i][j] = 0.0f;

    for (int kt = 0; kt < 64; kt += 32) {
        __syncthreads();
#pragma unroll
        for (int r = 0; r < 2; ++r) {
            int m = m0 + lm + 32 * r;
            size_t arow = (size_t)(m >> tcs) * 512 + t0 + (m & tcm);
            float4 v = *(const float4*)&A[arow * 64 + kt + lk];
            int ml = lm + 32 * r;
            As[lk + 0][ml] = v.x; As[lk + 1][ml] = v.y;
            As[lk + 2][ml] = v.z; As[lk + 3][ml] = v.w;
        }
#pragma unroll
        for (int r = 0; r < 4; ++r) {
            int n = lm + 32 * r;
            float4 v = *(const float4*)&Bm[(size_t)(n0 + n) * 64 + kt + lk];
            Bs[lk + 0][n] = v.x; Bs[lk + 1][n] = v.y;
            Bs[lk + 2][n] = v.z; Bs[lk + 3][n] = v.w;
        }
        __syncthreads();
#pragma unroll
        for (int k = 0; k < 32; ++k) {
            float4 a4 = *(const float4*)&As[k][ty * 4];
            float4 b0 = *(const float4*)&Bs[k][tx * 8];
            float4 b1 = *(const float4*)&Bs[k][tx * 8 + 4];
            float av[4] = {a4.x, a4.y, a4.z, a4.w};
            float bv[8] = {b0.x, b0.y, b0.z, b0.w, b1.x, b1.y, b1.z, b1.w};
#pragma unroll
            for (int i = 0; i < 4; ++i)
#pragma unroll
                for (int j = 0; j < 8; ++j)
                    acc[i][j] = fmaf(av[i], bv[j], acc[i][j]);
        }
    }
    float bb[8];
#pragma unroll
    for (int j = 0; j < 8; ++j) {
        int n = n0 + tx * 8 + j;
        bb[j] = bih[n] + bhh[n];
    }
#pragma unroll
    for (int i = 0; i < 4; ++i) {
        size_t row = (size_t)(m0 + ty * 4 + i) * 512 + n0 + tx * 8;
        *(float4*)&C[row]     = make_float4(acc[i][0] + bb[0], acc[i][1] + bb[1],
                                            acc[i][2] + bb[2], acc[i][3] + bb[3]);
        *(float4*)&C[row + 4] = make_float4(acc[i][4] + bb[4], acc[i][5] + bb[5],
                                            acc[i][6] + bb[6], acc[i][7] + bb[7]);
    }
}

// ---------------------------------------------------------------------------
// K6: P1[mc][g] = bih1[g]+bhh1[g] + H0c[mc][:] · Wih1[g][:]   (NT GEMM, K=128)
// ---------------------------------------------------------------------------
__global__ __launch_bounds__(256) void k_pre1gemm(const float* __restrict__ A,
                                                  const float* __restrict__ Bm,
                                                  const float* __restrict__ bih,
                                                  const float* __restrict__ bhh,
                                                  float* __restrict__ C) {
    __shared__ float As[32][68];
    __shared__ float Bs[32][132];
    const int n0 = blockIdx.x * 128;
    const int m0 = blockIdx.y * 64;
    const int tid = threadIdx.x;
    const int tx = tid & 15;
    const int ty = tid >> 4;
    const int lm = tid >> 3;
    const int lk = (tid & 7) * 4;
    float acc[4][8];
#pragma unroll
    for (int i = 0; i < 4; ++i)
#pragma unroll
        for (int j = 0; j < 8; ++j) acc[i][j] = 0.0f;

    for (int kt = 0; kt < 128; kt += 32) {
        __syncthreads();
#pragma unroll
        for (int r = 0; r < 2; ++r) {
            int m = lm + 32 * r;
            float4 v = *(const float4*)&A[(size_t)(m0 + m) * 128 + kt + lk];
            As[lk + 0][m] = v.x; As[lk + 1][m] = v.y;
            As[lk + 2][m] = v.z; As[lk + 3][m] = v.w;
        }
#pragma unroll
        for (int r = 0; r < 4; ++r) {
            int n = lm + 32 * r;
            float4 v = *(const float4*)&Bm[(size_t)(n0 + n) * 128 + kt + lk];
            Bs[lk + 0][n] = v.x; Bs[lk + 1][n] = v.y;
            Bs[lk + 2][n] = v.z; Bs[lk + 3][n] = v.w;
        }
        __syncthreads();
#pragma unroll
        for (int k = 0; k < 32; ++k) {
            float4 a4 = *(const float4*)&As[k][ty * 4];
            float4 b0 = *(const float4*)&Bs[k][tx * 8];
            float4 b1 = *(const float4*)&Bs[k][tx * 8 + 4];
            float av[4] = {a4.x, a4.y, a4.z, a4.w};
            float bv[8] = {b0.x, b0.y, b0.z, b0.w, b1.x, b1.y, b1.z, b1.w};
#pragma unroll
            for (int i = 0; i < 4; ++i)
#pragma unroll
                for (int j = 0; j < 8; ++j)
                    acc[i][j] = fmaf(av[i], bv[j], acc[i][j]);
        }
    }
    float bb[8];
#pragma unroll
    for (int j = 0; j < 8; ++j) {
        int n = n0 + tx * 8 + j;
        bb[j] = bih[n] + bhh[n];
    }
#pragma unroll
    for (int i = 0; i < 4; ++i) {
        size_t row = (size_t)(m0 + ty * 4 + i) * 512 + n0 + tx * 8;
        *(float4*)&C[row]     = make_float4(acc[i][0] + bb[0], acc[i][1] + bb[1],
                                            acc[i][2] + bb[2], acc[i][3] + bb[3]);
        *(float4*)&C[row + 4] = make_float4(acc[i][4] + bb[4], acc[i][5] + bb[5],
                                            acc[i][6] + bb[6], acc[i][7] + bb[7]);
    }
}

// ---------------------------------------------------------------------------
// K7: unified LSTM recurrence over one t-chunk. P holds pre-gates (incl. all
// biases). Split-K over 2 thread-halves; w[64] per thread (runtime offset ->
// fits the 128-VGPR budget, no spill). Optional per-step h store (layer 0).
// ---------------------------------------------------------------------------
__global__ __launch_bounds__(1024, 4) void k_rec(const float* __restrict__ P,
                                                 const float* __restrict__ Whh,
                                                 float* __restrict__ S,
                                                 float* __restrict__ Hout,
                                                 int TC) {
    __shared__ float hl[128];
    __shared__ float gl[2][512];
    const int b = blockIdx.x;
    const int tid = threadIdx.x;
    const int g = tid & 511;
    const int half = tid >> 9;
    const int lane = tid & 63;
    float w[64];
#pragma unroll
    for (int j = 0; j < 64; ++j) w[j] = Whh[(size_t)g * 128 + half * 64 + j];
    float c = 0.0f;
    if (tid < 128) {
        hl[tid] = S[(size_t)b * 128 + tid];
        c = S[32768 + (size_t)b * 128 + tid];
    }
    __syncthreads();
    const float* pb = P + (size_t)b * TC * 512;
    float* hb = Hout + (size_t)b * TC * 128;   // only dereferenced if Hout!=null
    const bool wr = (Hout != nullptr);
    float vp = (half == 0) ? pb[g] : 0.0f;
    for (int tl = 0; tl < TC; ++tl) {
        float vpn = (half == 0) ? pb[(size_t)(tl + 1) * 512 + g] : 0.0f;  // P padded
        float vh = (half == 0) ? hl[lane] : hl[64 + lane];
        float a0 = 0.f, a1 = 0.f, a2 = 0.f, a3 = 0.f;
#pragma unroll
        for (int j = 0; j < 64; j += 4) {
            a0 = fmaf(bcast(vh, j + 0), w[j + 0], a0);
            a1 = fmaf(bcast(vh, j + 1), w[j + 1], a1);
            a2 = fmaf(bcast(vh, j + 2), w[j + 2], a2);
            a3 = fmaf(bcast(vh, j + 3), w[j + 3], a3);
        }
        gl[half][g] = vp + ((a0 + a1) + (a2 + a3));
        __syncthreads();
        if (tid < 128) {
            float iv = fsigm(gl[0][tid]       + gl[1][tid]);
            float fv = fsigm(gl[0][128 + tid] + gl[1][128 + tid]);
            float gv = ftanh(gl[0][256 + tid] + gl[1][256 + tid]);
            float ov = fsigm(gl[0][384 + tid] + gl[1][384 + tid]);
            c = fv * c + iv * gv;
            float h = ov * ftanh(c);
            hl[tid] = h;
            if (wr) hb[(size_t)tl * 128 + tid] = h;
        }
        __syncthreads();
        vp = vpn;
    }
    if (tid < 128) {
        S[(size_t)b * 128 + tid] = hl[tid];
        S[32768 + (size_t)b * 128 + tid] = c;
    }
}

// ---------------------------------------------------------------------------
// K8: tail head: out = tanh(tanh(h1_last) @ W2^T + b2) @ W3^T + b3
// ---------------------------------------------------------------------------
__global__ __launch_bounds__(64) void k_tail(const float* __restrict__ Hs,
                                             const float* __restrict__ W2,
                                             const float* __restrict__ b2,
                                             const float* __restrict__ W3,
                                             const float* __restrict__ b3,
                                             float* __restrict__ out) {
    __shared__ float last[128], l2s[64];
    const int b = blockIdx.x, tid = threadIdx.x;
    last[tid]      = ftanh(Hs[(size_t)b * 128 + tid]);
    last[tid + 64] = ftanh(Hs[(size_t)b * 128 + 64 + tid]);
    __syncthreads();
    float acc = b2[tid];
#pragma unroll 4
    for (int j = 0; j < 128; ++j) acc = fmaf(W2[(size_t)tid * 128 + j], last[j], acc);
    l2s[tid] = ftanh(acc);
    __syncthreads();
    if (tid < 32) {
        float a2 = b3[tid];
#pragma unroll 4
        for (int o = 0; o < 64; ++o) a2 = fmaf(W3[(size_t)tid * 64 + o], l2s[o], a2);
        out[(size_t)b * 32 + tid] = a2;
    }
}

// ---------------------------------------------------------------------------
extern "C" void kernel_launch(void* const* d_in, const int* in_sizes, int n_in,
                              void* d_out, int out_size, void* d_ws, size_t ws_size,
                              hipStream_t stream) {
    (void)in_sizes; (void)n_in; (void)out_size;
    const float* inp  = (const float*)d_in[0];
    const float* akey = (const float*)d_in[1];
    const float* aval = (const float*)d_in[2];
    const float* W1   = (const float*)d_in[3];
    const float* b1   = (const float*)d_in[4];
    const float* Wih0 = (const float*)d_in[5];
    const float* Whh0 = (const float*)d_in[6];
    const float* bih0 = (const float*)d_in[7];
    const float* bhh0 = (const float*)d_in[8];
    const float* Wih1 = (const float*)d_in[9];
    const float* Whh1 = (const float*)d_in[10];
    const float* bih1 = (const float*)d_in[11];
    const float* bhh1 = (const float*)d_in[12];
    const float* W2   = (const float*)d_in[13];
    const float* b2   = (const float*)d_in[14];
    const float* W3   = (const float*)d_in[15];
    const float* b3   = (const float*)d_in[16];

    float* ws   = (float*)d_ws;
    float* dist = ws;                       // 2,097,152
    float* hist = dist + 2097152;           //   139,264
    float* X    = hist + 139264;            // 8,388,608 + 64 pad
    float* S0   = X + 8388672;              //    65,536 (h then c)
    float* S1   = S0 + 65536;               //    65,536
    float* H0c  = S1 + 65536;               // 256*TC*128
    const size_t fixed = (size_t)(H0c - ws);

    // per-TC floats: H0c 256*TC*128 + P0 (256*TC*512+512) + P1 (256*TC*512+512)
    int TC = 32, tcs = 5;
    if ((fixed + 294912ull * 128 + 1024) * 4 <= ws_size)      { TC = 128; tcs = 7; }
    else if ((fixed + 294912ull * 64 + 1024) * 4 <= ws_size)  { TC = 64;  tcs = 6; }
    float* P0 = H0c + (size_t)256 * TC * 128;
    float* P1 = P0 + (size_t)256 * TC * 512 + 512;

    k_dist<<<dim3(64, 4), 256, 0, stream>>>(inp, akey, dist);
    k_softmax<<<256, 256, 0, stream>>>(dist);
    hipMemsetAsync(hist, 0, 139264 * 4, stream);
    k_hist<<<dim3(9, 4, 8), 256, 0, stream>>>(dist, aval, hist);
    k_xfeat<<<dim3(4, 256), 256, 0, stream>>>(inp, hist, W1, b1, X);
    hipMemsetAsync(S0, 0, (size_t)2 * 65536 * 4, stream);  // S0+S1 contiguous
    for (int t0 = 0; t0 < 512; t0 += TC) {
        k_pre0gemm<<<dim3(4, 256 * TC / 64), 256, 0, stream>>>(X, Wih0, bih0, bhh0, P0, t0, tcs);
        k_rec<<<256, 1024, 0, stream>>>(P0, Whh0, S0, H0c, TC);
        k_pre1gemm<<<dim3(4, 256 * TC / 64), 256, 0, stream>>>(H0c, Wih1, bih1, bhh1, P1);
        k_rec<<<256, 1024, 0, stream>>>(P1, Whh1, S1, nullptr, TC);
    }
    k_tail<<<256, 64, 0, stream>>>(S1, W2, b2, W3, b3, (float*)d_out);
}